// Round 9
// baseline (66.227 us; speedup 1.0000x reference)
//
#include <hip/hip_runtime.h>
#include <hip/hip_bf16.h>

// DenseFastGAT  B=2, N=4096, IN=OUT=256, ~1%-dense adjacency given dense.
//   K1 gat_zgemm : zb = bf16(x@W^T + bW); partial ai/aj dots -> pai/paj.
//   K2 gat_fused : 1024 blocks x 4 waves; wave owns rows 2gw, 2gw+1.
//                  Pipeline: stream row0 -> compact -> issue row1 stream ->
//                  attend row0 (overlaps row1 HBM) -> compact row1 -> attend.
//                  No launch_bounds VGPR cap (R4's spill bug), no global mask,
//                  no __syncthreads (per-wave LDS strips).

#define NN   4096
#define OUTF 256
#define INF  256
#define CAP_E 128      // max edges/row; Binom(4096,0.01) max ~75, hard-guarded

typedef __attribute__((ext_vector_type(8))) short short8v;
typedef __attribute__((ext_vector_type(4))) float f32x4;

static __device__ __forceinline__ unsigned short f2bf(float f) {
    union { float f; unsigned u; } v; v.f = f;
    unsigned r = v.u + 0x7fffu + ((v.u >> 16) & 1u);   // RNE (finite inputs)
    return (unsigned short)(r >> 16);
}
static __device__ __forceinline__ float bf2f(unsigned short u) {
    union { unsigned u; float f; } v; v.u = ((unsigned)u) << 16; return v.f;
}

// ---------------------------------------------------------------- K1: z GEMM
// M=8192, N=256, K=256. BM=64, BN=64, BK=64, 4 waves (2x2 of 32x32).
#define BM 64
#define BN 64
#define BK 64

__global__ __launch_bounds__(256) void gat_zgemm(
        const float* __restrict__ x, const float* __restrict__ W,
        const float* __restrict__ bW, const float* __restrict__ wai,
        const float* __restrict__ waj, unsigned short* __restrict__ zb,
        float* __restrict__ pai, float* __restrict__ paj) {
    __shared__ alignas(16) unsigned short As[BM * BK];  // row stride 128B, XOR-swz
    __shared__ alignas(16) unsigned short Bs[BN * BK];
    const int tid  = threadIdx.x;
    const int lane = tid & 63;
    const int wid  = tid >> 6;
    const int rowBase = blockIdx.x * BM;
    const int colBase = blockIdx.y * BN;
    const int wm = (wid >> 1) * 32;
    const int wn = (wid & 1) * 32;
    const int sr = tid >> 4;          // staging row 0..15
    const int sc = tid & 15;          // staging col-quad

    f32x4 acc[2][2] = {};

    for (int kk = 0; kk < INF; kk += BK) {
        #pragma unroll
        for (int pass = 0; pass < BM / 16; ++pass) {
            int r = pass * 16 + sr;
            const float4 v = *(const float4*)(&x[(size_t)(rowBase + r) * INF + kk + sc * 4]);
            int off = r * 128 + ((sc * 8) ^ ((r & 7) << 4));
            *(ushort4*)((char*)As + off) =
                make_ushort4(f2bf(v.x), f2bf(v.y), f2bf(v.z), f2bf(v.w));
        }
        #pragma unroll
        for (int pass = 0; pass < BN / 16; ++pass) {
            int r = pass * 16 + sr;
            const float4 v = *(const float4*)(&W[(size_t)(colBase + r) * INF + kk + sc * 4]);
            int off = r * 128 + ((sc * 8) ^ ((r & 7) << 4));
            *(ushort4*)((char*)Bs + off) =
                make_ushort4(f2bf(v.x), f2bf(v.y), f2bf(v.z), f2bf(v.w));
        }
        __syncthreads();
        #pragma unroll
        for (int ks = 0; ks < 2; ++ks) {
            short8v aF[2], bF[2];
            #pragma unroll
            for (int m = 0; m < 2; ++m) {
                int row = wm + m * 16 + (lane & 15);
                int cb  = (ks * 64 + ((lane >> 4) * 16)) ^ ((row & 7) << 4);
                aF[m] = *(const short8v*)((const char*)As + row * 128 + cb);
            }
            #pragma unroll
            for (int n = 0; n < 2; ++n) {
                int row = wn + n * 16 + (lane & 15);
                int cb  = (ks * 64 + ((lane >> 4) * 16)) ^ ((row & 7) << 4);
                bF[n] = *(const short8v*)((const char*)Bs + row * 128 + cb);
            }
            #pragma unroll
            for (int m = 0; m < 2; ++m)
                #pragma unroll
                for (int n = 0; n < 2; ++n)
                    acc[m][n] = __builtin_amdgcn_mfma_f32_16x16x32_bf16(
                        aF[m], bF[n], acc[m][n], 0, 0, 0);
        }
        __syncthreads();
    }
    // epilogue: C/D layout col=lane&15, row=(lane>>4)*4+reg
    const int r4 = (lane >> 4) * 4;
    const int cW = lane & 15;
    const int col0 = colBase + wn + cW;
    const int col1 = col0 + 16;
    const float b0 = bW[col0],  b1 = bW[col1];
    const float i0 = wai[col0], i1 = wai[col1];
    const float j0 = waj[col0], j1 = waj[col1];
    const int slot = blockIdx.y * 2 + (wid & 1);   // 8 x 32-col slices per row
    #pragma unroll
    for (int m = 0; m < 2; ++m) {
        #pragma unroll
        for (int r = 0; r < 4; ++r) {
            int row = rowBase + wm + m * 16 + r4 + r;
            float z0 = acc[m][0][r] + b0;
            float z1 = acc[m][1][r] + b1;
            zb[(size_t)row * OUTF + col0] = f2bf(z0);
            zb[(size_t)row * OUTF + col1] = f2bf(z1);
            float pi = z0 * i0 + z1 * i1;
            float pj = z0 * j0 + z1 * j1;
            #pragma unroll
            for (int s = 1; s < 16; s <<= 1) {   // 16-lane group reduce
                pi += __shfl_xor(pi, s);
                pj += __shfl_xor(pj, s);
            }
            if (cW == 0) {
                pai[row * 8 + slot] = pi;
                paj[row * 8 + slot] = pj;
            }
        }
    }
}

// ----------------------------------------------------------- K2 helpers
static __device__ __forceinline__ int compact16(const float4 (&vv)[16], int lane,
                                                unsigned short* __restrict__ si) {
    int base = 0;
    #pragma unroll
    for (int t = 0; t < 16; ++t) {
        const float4 v = vv[t];
        int pred = (v.x > 0.f ? 1 : 0) | (v.y > 0.f ? 2 : 0) |
                   (v.z > 0.f ? 4 : 0) | (v.w > 0.f ? 8 : 0);
        unsigned long long b0 = __ballot(pred & 1);
        unsigned long long b1 = __ballot((pred >> 1) & 1);
        unsigned long long b2 = __ballot((pred >> 2) & 1);
        unsigned long long b3 = __ballot((pred >> 3) & 1);
        unsigned long long below = (1ull << lane) - 1ull;
        int pos = base + __popcll(b0 & below) + __popcll(b1 & below) +
                         __popcll(b2 & below) + __popcll(b3 & below);
        int jb = (t * 64 + lane) * 4;
        if (pred & 1) { if (pos < CAP_E) si[pos] = (unsigned short)jb;       ++pos; }
        if (pred & 2) { if (pos < CAP_E) si[pos] = (unsigned short)(jb + 1); ++pos; }
        if (pred & 4) { if (pos < CAP_E) si[pos] = (unsigned short)(jb + 2); ++pos; }
        if (pred & 8) { if (pos < CAP_E) si[pos] = (unsigned short)(jb + 3); ++pos; }
        base += __popcll(b0) + __popcll(b1) + __popcll(b2) + __popcll(b3);
    }
    return base > CAP_E ? CAP_E : base;
}

static __device__ __forceinline__ void attendRow(
        int row, int b, int cnt, int lane,
        unsigned short* __restrict__ si, float* __restrict__ swv,
        const float* __restrict__ pai, const float* __restrict__ paj,
        float bsum, const unsigned short* __restrict__ zb,
        float* __restrict__ out) {
    // AI = sum(pai[row]) + bai + baj   (both biases folded into the i-term)
    const float4* pa = (const float4*)(pai + row * 8);
    const float4 u = pa[0], v2 = pa[1];
    const float AI = (u.x + u.y + u.z + u.w) + (v2.x + v2.y + v2.z + v2.w) + bsum;

    // per-lane aj finalize for edge slots lane and lane+64 (cnt <= 128)
    const bool h0 = lane < cnt, h1 = lane + 64 < cnt;
    float a0 = -3e38f, a1 = -3e38f;
    const float* pjb = paj + ((size_t)(b << 12)) * 8;
    if (h0) {
        const float4* q = (const float4*)(pjb + si[lane] * 8);
        float4 x0 = q[0], x1 = q[1];
        a0 = (x0.x + x0.y + x0.z + x0.w) + (x1.x + x1.y + x1.z + x1.w);
    }
    if (h1) {
        const float4* q = (const float4*)(pjb + si[lane + 64] * 8);
        float4 x0 = q[0], x1 = q[1];
        a1 = (x0.x + x0.y + x0.z + x0.w) + (x1.x + x1.y + x1.z + x1.w);
    }
    float lm = fmaxf(a0, a1);
    #pragma unroll
    for (int s = 1; s < 64; s <<= 1) lm = fmaxf(lm, __shfl_xor(lm, s));
    const float tm = AI + lm;
    const float m = tm >= 0.f ? tm : 0.2f * tm;    // leaky is monotone
    float w0 = 0.f, w1 = 0.f;
    if (h0) { float e = AI + a0; e = e >= 0.f ? e : 0.2f * e; w0 = __expf(e - m); }
    if (h1) { float e = AI + a1; e = e >= 0.f ? e : 0.2f * e; w1 = __expf(e - m); }
    float ls = w0 + w1;
    #pragma unroll
    for (int s = 1; s < 64; s <<= 1) ls += __shfl_xor(ls, s);
    const float inv = cnt ? 1.f / ls : 0.f;
    if (h0) swv[lane] = w0;
    if (h1) swv[lane + 64] = w1;

    // gather: out[row][lane*4 .. +3] = inv * sum_p w_p * zb[j_p][cols]
    const unsigned short* zcol = zb + ((size_t)(b << 12)) * OUTF + lane * 4;
    float4 acc = make_float4(0.f, 0.f, 0.f, 0.f);
    int p = 0;
    for (; p + 4 <= cnt; p += 4) {
        int   g0 = si[p],  g1 = si[p + 1], g2 = si[p + 2], g3 = si[p + 3];
        float W0 = swv[p], W1 = swv[p + 1], W2 = swv[p + 2], W3 = swv[p + 3];
        ushort4 q0 = *(const ushort4*)(zcol + (size_t)g0 * OUTF);
        ushort4 q1 = *(const ushort4*)(zcol + (size_t)g1 * OUTF);
        ushort4 q2 = *(const ushort4*)(zcol + (size_t)g2 * OUTF);
        ushort4 q3 = *(const ushort4*)(zcol + (size_t)g3 * OUTF);
        acc.x = fmaf(W0, bf2f(q0.x), fmaf(W1, bf2f(q1.x), fmaf(W2, bf2f(q2.x), fmaf(W3, bf2f(q3.x), acc.x))));
        acc.y = fmaf(W0, bf2f(q0.y), fmaf(W1, bf2f(q1.y), fmaf(W2, bf2f(q2.y), fmaf(W3, bf2f(q3.y), acc.y))));
        acc.z = fmaf(W0, bf2f(q0.z), fmaf(W1, bf2f(q1.z), fmaf(W2, bf2f(q2.z), fmaf(W3, bf2f(q3.z), acc.z))));
        acc.w = fmaf(W0, bf2f(q0.w), fmaf(W1, bf2f(q1.w), fmaf(W2, bf2f(q2.w), fmaf(W3, bf2f(q3.w), acc.w))));
    }
    for (; p < cnt; ++p) {
        int g = si[p]; float Wp = swv[p];
        ushort4 q = *(const ushort4*)(zcol + (size_t)g * OUTF);
        acc.x = fmaf(Wp, bf2f(q.x), acc.x);
        acc.y = fmaf(Wp, bf2f(q.y), acc.y);
        acc.z = fmaf(Wp, bf2f(q.z), acc.z);
        acc.w = fmaf(Wp, bf2f(q.w), acc.w);
    }
    *(float4*)(out + (size_t)row * OUTF + lane * 4) =
        make_float4(acc.x * inv, acc.y * inv, acc.z * inv, acc.w * inv);
}

// --------------------------------------- K2: pipelined scan+softmax+gather
// 1024 blocks x 4 waves = 4096 waves; wave gw handles rows 2gw and 2gw+1
// (32KB contiguous adj per wave). Row1's stream issues before row0's attend,
// so HBM stays busy during softmax+gather. No VGPR cap -> no spill (R4 bug).
__global__ __launch_bounds__(256) void gat_fused(
        const float* __restrict__ adj, const float* __restrict__ pai,
        const float* __restrict__ paj, const float* __restrict__ bai,
        const float* __restrict__ baj, const unsigned short* __restrict__ zb,
        float* __restrict__ out) {
    __shared__ unsigned short s_idx[4][CAP_E];   // per-wave edge strip
    __shared__ float          s_w[4][CAP_E];
    const int tid  = threadIdx.x;
    const int lane = tid & 63;
    const int wv   = tid >> 6;
    const int gw   = blockIdx.x * 4 + wv;        // 0..4095
    unsigned short* si = s_idx[wv];
    float* swv = s_w[wv];

    const float bsum = bai[0] + baj[0];
    const int row0 = gw * 2;
    const int row1 = row0 + 1;
    const int b    = row0 >> 12;                 // rows share the batch

    // stream row0
    const float4* a4 = (const float4*)adj;
    float4 vv[16];
    #pragma unroll
    for (int t = 0; t < 16; ++t) vv[t] = a4[((size_t)row0 * 16 + t) * 64 + lane];

    const int cnt0 = compact16(vv, lane, si);

    // issue row1's stream — overlaps row0's attend
    #pragma unroll
    for (int t = 0; t < 16; ++t) vv[t] = a4[((size_t)row1 * 16 + t) * 64 + lane];

    attendRow(row0, b, cnt0, lane, si, swv, pai, paj, bsum, zb, out);

    const int cnt1 = compact16(vv, lane, si);
    attendRow(row1, b, cnt1, lane, si, swv, pai, paj, bsum, zb, out);
}

extern "C" void kernel_launch(void* const* d_in, const int* in_sizes, int n_in,
                              void* d_out, int out_size, void* d_ws, size_t ws_size,
                              hipStream_t stream) {
    const float* x   = (const float*)d_in[0];
    const float* adj = (const float*)d_in[1];
    const float* W   = (const float*)d_in[2];
    const float* bW  = (const float*)d_in[3];
    const float* wai = (const float*)d_in[4];
    const float* bai = (const float*)d_in[5];
    const float* waj = (const float*)d_in[6];
    const float* baj = (const float*)d_in[7];
    float* out = (float*)d_out;

    char* ws = (char*)d_ws;
    unsigned short* zb = (unsigned short*)ws;                 // 4 MB
    float* pai = (float*)(ws + (4u << 20));                   // 256 KB
    float* paj = pai + 8192 * 8;                              // 256 KB

    gat_zgemm<<<dim3(8192 / BM, OUTF / BN), 256, 0, stream>>>(
        x, W, bW, wai, waj, zb, pai, paj);
    gat_fused<<<1024, 256, 0, stream>>>(adj, pai, paj, bai, baj, zb, out);
}

// Round 10
// 52.489 us; speedup vs baseline: 1.2617x; 1.2617x over previous
//
#include <hip/hip_runtime.h>
#include <hip/hip_bf16.h>

// DenseFastGAT  B=2, N=4096, IN=OUT=256, ~1%-dense adjacency given dense.
//   K1 gat_pre   : block-specialized. Blocks [0,512): zb = bf16(x@W^T + bW) +
//                  partial ai/aj dots. Blocks [512,2560): adj fp32 -> bitmask
//                  via NON-TEMPORAL lane-contiguous float4 + 4 ballots per 1KB
//                  chunk (adj is read-once; keep L2/L3 for zb/mask/paj).
//   K2 gat_attend: wave per row (linear bid map). 512B bitmask/row ->
//                  popcount prefix compaction, softmax, zb gather (unroll 8).
// Mask bit layout: word w of row r (w in [0,64)) = ballot of chunk c=w>>2,
// component w&3: bit l  <->  j = (w>>2)*256 + l*4 + (w&3).

#define NN   4096
#define OUTF 256
#define INF  256
#define CAP_E 128      // max edges/row; Binom(4096,0.01) max ~75, hard-guarded

typedef __attribute__((ext_vector_type(8))) short short8v;
typedef __attribute__((ext_vector_type(4))) float f32x4;

static __device__ __forceinline__ unsigned short f2bf(float f) {
    union { float f; unsigned u; } v; v.f = f;
    unsigned r = v.u + 0x7fffu + ((v.u >> 16) & 1u);   // RNE (finite inputs)
    return (unsigned short)(r >> 16);
}
static __device__ __forceinline__ float bf2f(unsigned short u) {
    union { unsigned u; float f; } v; v.u = ((unsigned)u) << 16; return v.f;
}

// ---------------------------------------------------------------- K1 fused
// GEMM geometry: M=8192, N=256, K=256. BM=64, BN=64, BK=64, 4 waves (2x2).
#define BM 64
#define BN 64
#define BK 64
#define GEMM_BLOCKS 512           // (8192/64) * (256/64)
#define MASK_BLOCKS 2048

__global__ __launch_bounds__(256) void gat_pre(
        const float* __restrict__ x, const float* __restrict__ W,
        const float* __restrict__ bW, const float* __restrict__ wai,
        const float* __restrict__ waj, unsigned short* __restrict__ zb,
        float* __restrict__ pai, float* __restrict__ paj,
        const float* __restrict__ adj, unsigned long long* __restrict__ mask64) {
    __shared__ alignas(16) unsigned short As[BM * BK];  // row stride 128B, XOR-swz
    __shared__ alignas(16) unsigned short Bs[BN * BK];
    const int tid  = threadIdx.x;
    const int lane = tid & 63;
    const int wid  = tid >> 6;

    if (blockIdx.x >= GEMM_BLOCKS) {
        // ---- mask path: wave streams 16 chunks of 1KB, lane-contiguous,
        // non-temporal (adj is never re-read; don't churn L2/L3).
        const int widx = (blockIdx.x - GEMM_BLOCKS) * 4 + wid;   // 0..8191
        const f32x4* a4 = (const f32x4*)adj;
        const size_t cbase = (size_t)widx * 16;
        #pragma unroll 4
        for (int c = 0; c < 16; ++c) {
            const f32x4 v = __builtin_nontemporal_load(&a4[(cbase + c) * 64 + lane]);
            unsigned long long b0 = __ballot(v.x > 0.f);
            unsigned long long b1 = __ballot(v.y > 0.f);
            unsigned long long b2 = __ballot(v.z > 0.f);
            unsigned long long b3 = __ballot(v.w > 0.f);
            if (lane == 0) {
                unsigned long long* dst = mask64 + (cbase + c) * 4;
                dst[0] = b0; dst[1] = b1; dst[2] = b2; dst[3] = b3;
            }
        }
        return;
    }

    // ---- GEMM path (blocks [0,512))
    const int rowBase = (blockIdx.x & 127) * BM;
    const int colBase = (blockIdx.x >> 7) * BN;
    const int wm = (wid >> 1) * 32;
    const int wn = (wid & 1) * 32;
    const int sr = tid >> 4;          // staging row 0..15
    const int sc = tid & 15;          // staging col-quad

    f32x4 acc[2][2] = {};

    for (int kk = 0; kk < INF; kk += BK) {
        #pragma unroll
        for (int pass = 0; pass < BM / 16; ++pass) {
            int r = pass * 16 + sr;
            const float4 v = *(const float4*)(&x[(size_t)(rowBase + r) * INF + kk + sc * 4]);
            int off = r * 128 + ((sc * 8) ^ ((r & 7) << 4));
            *(ushort4*)((char*)As + off) =
                make_ushort4(f2bf(v.x), f2bf(v.y), f2bf(v.z), f2bf(v.w));
        }
        #pragma unroll
        for (int pass = 0; pass < BN / 16; ++pass) {
            int r = pass * 16 + sr;
            const float4 v = *(const float4*)(&W[(size_t)(colBase + r) * INF + kk + sc * 4]);
            int off = r * 128 + ((sc * 8) ^ ((r & 7) << 4));
            *(ushort4*)((char*)Bs + off) =
                make_ushort4(f2bf(v.x), f2bf(v.y), f2bf(v.z), f2bf(v.w));
        }
        __syncthreads();
        #pragma unroll
        for (int ks = 0; ks < 2; ++ks) {
            short8v aF[2], bF[2];
            #pragma unroll
            for (int m = 0; m < 2; ++m) {
                int row = wm + m * 16 + (lane & 15);
                int cb  = (ks * 64 + ((lane >> 4) * 16)) ^ ((row & 7) << 4);
                aF[m] = *(const short8v*)((const char*)As + row * 128 + cb);
            }
            #pragma unroll
            for (int n = 0; n < 2; ++n) {
                int row = wn + n * 16 + (lane & 15);
                int cb  = (ks * 64 + ((lane >> 4) * 16)) ^ ((row & 7) << 4);
                bF[n] = *(const short8v*)((const char*)Bs + row * 128 + cb);
            }
            #pragma unroll
            for (int m = 0; m < 2; ++m)
                #pragma unroll
                for (int n = 0; n < 2; ++n)
                    acc[m][n] = __builtin_amdgcn_mfma_f32_16x16x32_bf16(
                        aF[m], bF[n], acc[m][n], 0, 0, 0);
        }
        __syncthreads();
    }
    // epilogue: C/D layout col=lane&15, row=(lane>>4)*4+reg
    const int r4 = (lane >> 4) * 4;
    const int cW = lane & 15;
    const int col0 = colBase + wn + cW;
    const int col1 = col0 + 16;
    const float b0 = bW[col0],  b1 = bW[col1];
    const float i0 = wai[col0], i1 = wai[col1];
    const float j0 = waj[col0], j1 = waj[col1];
    const int slot = (blockIdx.x >> 7) * 2 + (wid & 1);   // 8 x 32-col slices
    #pragma unroll
    for (int m = 0; m < 2; ++m) {
        #pragma unroll
        for (int r = 0; r < 4; ++r) {
            int row = rowBase + wm + m * 16 + r4 + r;
            float z0 = acc[m][0][r] + b0;
            float z1 = acc[m][1][r] + b1;
            zb[(size_t)row * OUTF + col0] = f2bf(z0);
            zb[(size_t)row * OUTF + col1] = f2bf(z1);
            float pi = z0 * i0 + z1 * i1;
            float pj = z0 * j0 + z1 * j1;
            #pragma unroll
            for (int s = 1; s < 16; s <<= 1) {   // 16-lane group reduce
                pi += __shfl_xor(pi, s);
                pj += __shfl_xor(pj, s);
            }
            if (cW == 0) {
                pai[row * 8 + slot] = pi;
                paj[row * 8 + slot] = pj;
            }
        }
    }
}

// ---------------------------------------------------- K2: sparse attention
// Wave per row (4/block, 2048 blocks, linear bid map). Lane holds mask word
// `lane`: j = (lane>>2)*256 + bit*4 + (lane&3). Popcount prefix-scan ->
// edge strip in per-wave LDS (no block barriers). Masked (-9e15) / sink
// (-1e9) reference terms underflow to exactly 0 for rows with edges;
// edgeless rows -> 0.
__global__ __launch_bounds__(256) void gat_attend(
        const unsigned long long* __restrict__ mask64,
        const float* __restrict__ pai, const float* __restrict__ paj,
        const float* __restrict__ bai, const float* __restrict__ baj,
        const unsigned short* __restrict__ zb, float* __restrict__ out) {
    __shared__ unsigned short s_idx[4][CAP_E];   // per-wave edge strip
    __shared__ float          s_w[4][CAP_E];
    const int tid  = threadIdx.x;
    const int lane = tid & 63;
    const int wv   = tid >> 6;
    const int row  = blockIdx.x * 4 + wv;
    const int b    = row >> 12;
    unsigned short* si = s_idx[wv];
    float* swv = s_w[wv];

    // compaction: 1 load + popcount prefix + per-lane bit extraction
    unsigned long long mm = mask64[(size_t)row * 64 + lane];
    const int c = __popcll(mm);
    int incl = c;
    #pragma unroll
    for (int s = 1; s < 64; s <<= 1) {
        int t = __shfl_up(incl, s);
        if (lane >= s) incl += t;
    }
    const int cnt0 = __shfl(incl, 63);
    const int cnt = cnt0 > CAP_E ? CAP_E : cnt0;
    int pos = incl - c;
    const int jbase = (lane >> 2) * 256 + (lane & 3);
    while (mm) {
        int bit = __builtin_ctzll(mm);
        if (pos < CAP_E) si[pos] = (unsigned short)(jbase + bit * 4);
        ++pos;
        mm &= mm - 1;
    }

    // AI = sum(pai[row]) + bai + baj  (both biases folded into the i-term)
    const float4* pa = (const float4*)(pai + row * 8);
    const float4 u = pa[0], v2 = pa[1];
    const float AI = (u.x + u.y + u.z + u.w) + (v2.x + v2.y + v2.z + v2.w)
                   + bai[0] + baj[0];

    // per-lane aj finalize for edge slots lane and lane+64 (cnt <= 128)
    const bool h0 = lane < cnt, h1 = lane + 64 < cnt;
    float a0 = -3e38f, a1 = -3e38f;
    const float* pjb = paj + ((size_t)(b << 12)) * 8;
    if (h0) {
        const float4* q = (const float4*)(pjb + si[lane] * 8);
        float4 x0 = q[0], x1 = q[1];
        a0 = (x0.x + x0.y + x0.z + x0.w) + (x1.x + x1.y + x1.z + x1.w);
    }
    if (h1) {
        const float4* q = (const float4*)(pjb + si[lane + 64] * 8);
        float4 x0 = q[0], x1 = q[1];
        a1 = (x0.x + x0.y + x0.z + x0.w) + (x1.x + x1.y + x1.z + x1.w);
    }
    float lm = fmaxf(a0, a1);
    #pragma unroll
    for (int s = 1; s < 64; s <<= 1) lm = fmaxf(lm, __shfl_xor(lm, s));
    const float tm = AI + lm;
    const float m = tm >= 0.f ? tm : 0.2f * tm;    // leaky is monotone
    float w0 = 0.f, w1 = 0.f;
    if (h0) { float e = AI + a0; e = e >= 0.f ? e : 0.2f * e; w0 = __expf(e - m); }
    if (h1) { float e = AI + a1; e = e >= 0.f ? e : 0.2f * e; w1 = __expf(e - m); }
    float ls = w0 + w1;
    #pragma unroll
    for (int s = 1; s < 64; s <<= 1) ls += __shfl_xor(ls, s);
    const float inv = cnt ? 1.f / ls : 0.f;
    if (h0) swv[lane] = w0;
    if (h1) swv[lane + 64] = w1;

    // gather: out[row][lane*4 .. +3] = inv * sum_p w_p * zb[j_p][cols]
    // unroll 8: 8 independent ushort4 loads in flight per iteration.
    const unsigned short* zcol = zb + ((size_t)(b << 12)) * OUTF + lane * 4;
    float4 acc = make_float4(0.f, 0.f, 0.f, 0.f);
    int p = 0;
    for (; p + 8 <= cnt; p += 8) {
        ushort4 q[8];
        float   w[8];
        #pragma unroll
        for (int k = 0; k < 8; ++k) {
            q[k] = *(const ushort4*)(zcol + (size_t)si[p + k] * OUTF);
            w[k] = swv[p + k];
        }
        #pragma unroll
        for (int k = 0; k < 8; ++k) {
            acc.x = fmaf(w[k], bf2f(q[k].x), acc.x);
            acc.y = fmaf(w[k], bf2f(q[k].y), acc.y);
            acc.z = fmaf(w[k], bf2f(q[k].z), acc.z);
            acc.w = fmaf(w[k], bf2f(q[k].w), acc.w);
        }
    }
    if (p + 4 <= cnt) {
        ushort4 q[4];
        float   w[4];
        #pragma unroll
        for (int k = 0; k < 4; ++k) {
            q[k] = *(const ushort4*)(zcol + (size_t)si[p + k] * OUTF);
            w[k] = swv[p + k];
        }
        #pragma unroll
        for (int k = 0; k < 4; ++k) {
            acc.x = fmaf(w[k], bf2f(q[k].x), acc.x);
            acc.y = fmaf(w[k], bf2f(q[k].y), acc.y);
            acc.z = fmaf(w[k], bf2f(q[k].z), acc.z);
            acc.w = fmaf(w[k], bf2f(q[k].w), acc.w);
        }
        p += 4;
    }
    for (; p < cnt; ++p) {
        int g = si[p]; float Wp = swv[p];
        ushort4 q = *(const ushort4*)(zcol + (size_t)g * OUTF);
        acc.x = fmaf(Wp, bf2f(q.x), acc.x);
        acc.y = fmaf(Wp, bf2f(q.y), acc.y);
        acc.z = fmaf(Wp, bf2f(q.z), acc.z);
        acc.w = fmaf(Wp, bf2f(q.w), acc.w);
    }
    *(float4*)(out + (size_t)row * OUTF + lane * 4) =
        make_float4(acc.x * inv, acc.y * inv, acc.z * inv, acc.w * inv);
}

extern "C" void kernel_launch(void* const* d_in, const int* in_sizes, int n_in,
                              void* d_out, int out_size, void* d_ws, size_t ws_size,
                              hipStream_t stream) {
    const float* x   = (const float*)d_in[0];
    const float* adj = (const float*)d_in[1];
    const float* W   = (const float*)d_in[2];
    const float* bW  = (const float*)d_in[3];
    const float* wai = (const float*)d_in[4];
    const float* bai = (const float*)d_in[5];
    const float* waj = (const float*)d_in[6];
    const float* baj = (const float*)d_in[7];
    float* out = (float*)d_out;

    char* ws = (char*)d_ws;
    unsigned short* zb   = (unsigned short*)ws;                    // 4 MB
    float* pai = (float*)(ws + (4u << 20));                        // 256 KB
    float* paj = pai + 8192 * 8;                                   // 256 KB
    unsigned long long* mask = (unsigned long long*)(ws + (5u << 20)); // 4 MB

    gat_pre<<<GEMM_BLOCKS + MASK_BLOCKS, 256, 0, stream>>>(
        x, W, bW, wai, waj, zb, pai, paj, adj, mask);
    gat_attend<<<2048, 256, 0, stream>>>(
        mask, pai, paj, bai, baj, zb, out);
}

// Round 11
// 44.956 us; speedup vs baseline: 1.4732x; 1.1676x over previous
//
#include <hip/hip_runtime.h>
#include <hip/hip_bf16.h>

// DenseFastGAT  B=2, N=4096, IN=OUT=256, ~1%-dense adjacency given dense.
//   K1 gat_pre   : block-specialized. Blocks [0,512): zb = bf16(x@W^T + bW) +
//                  partial ai/aj dots. Blocks [512,2560): adj fp32 -> bitmask
//                  via plain lane-contiguous float4 + 4 ballots per 1KB chunk
//                  (R7 pattern; NT experiment reverted). GEMM hides under the
//                  adj stream.
//   K2 gat_attend: wave per row (linear bid map). 512B bitmask/row ->
//                  popcount prefix compaction, softmax, zb gather (unroll 8).
// Mask bit layout: word w of row r (w in [0,64)) = ballot of chunk c=w>>2,
// component w&3: bit l  <->  j = (w>>2)*256 + l*4 + (w&3).

#define NN   4096
#define OUTF 256
#define INF  256
#define CAP_E 128      // max edges/row; Binom(4096,0.01) max ~75, hard-guarded

typedef __attribute__((ext_vector_type(8))) short short8v;
typedef __attribute__((ext_vector_type(4))) float f32x4;

static __device__ __forceinline__ unsigned short f2bf(float f) {
    union { float f; unsigned u; } v; v.f = f;
    unsigned r = v.u + 0x7fffu + ((v.u >> 16) & 1u);   // RNE (finite inputs)
    return (unsigned short)(r >> 16);
}
static __device__ __forceinline__ float bf2f(unsigned short u) {
    union { unsigned u; float f; } v; v.u = ((unsigned)u) << 16; return v.f;
}

// ---------------------------------------------------------------- K1 fused
// GEMM geometry: M=8192, N=256, K=256. BM=64, BN=64, BK=64, 4 waves (2x2).
#define BM 64
#define BN 64
#define BK 64
#define GEMM_BLOCKS 512           // (8192/64) * (256/64)
#define MASK_BLOCKS 2048

__global__ __launch_bounds__(256) void gat_pre(
        const float* __restrict__ x, const float* __restrict__ W,
        const float* __restrict__ bW, const float* __restrict__ wai,
        const float* __restrict__ waj, unsigned short* __restrict__ zb,
        float* __restrict__ pai, float* __restrict__ paj,
        const float* __restrict__ adj, unsigned long long* __restrict__ mask64) {
    __shared__ alignas(16) unsigned short As[BM * BK];  // row stride 128B, XOR-swz
    __shared__ alignas(16) unsigned short Bs[BN * BK];
    const int tid  = threadIdx.x;
    const int lane = tid & 63;
    const int wid  = tid >> 6;

    if (blockIdx.x >= GEMM_BLOCKS) {
        // ---- mask path: wave streams 16 chunks of 1KB, lane-contiguous.
        const int widx = (blockIdx.x - GEMM_BLOCKS) * 4 + wid;   // 0..8191
        const float4* a4 = (const float4*)adj;
        const size_t cbase = (size_t)widx * 16;
        #pragma unroll 4
        for (int c = 0; c < 16; ++c) {
            const float4 v = a4[(cbase + c) * 64 + lane];
            unsigned long long b0 = __ballot(v.x > 0.f);
            unsigned long long b1 = __ballot(v.y > 0.f);
            unsigned long long b2 = __ballot(v.z > 0.f);
            unsigned long long b3 = __ballot(v.w > 0.f);
            if (lane == 0) {
                unsigned long long* dst = mask64 + (cbase + c) * 4;
                dst[0] = b0; dst[1] = b1; dst[2] = b2; dst[3] = b3;
            }
        }
        return;
    }

    // ---- GEMM path (blocks [0,512))
    const int rowBase = (blockIdx.x & 127) * BM;
    const int colBase = (blockIdx.x >> 7) * BN;
    const int wm = (wid >> 1) * 32;
    const int wn = (wid & 1) * 32;
    const int sr = tid >> 4;          // staging row 0..15
    const int sc = tid & 15;          // staging col-quad

    f32x4 acc[2][2] = {};

    for (int kk = 0; kk < INF; kk += BK) {
        #pragma unroll
        for (int pass = 0; pass < BM / 16; ++pass) {
            int r = pass * 16 + sr;
            const float4 v = *(const float4*)(&x[(size_t)(rowBase + r) * INF + kk + sc * 4]);
            int off = r * 128 + ((sc * 8) ^ ((r & 7) << 4));
            *(ushort4*)((char*)As + off) =
                make_ushort4(f2bf(v.x), f2bf(v.y), f2bf(v.z), f2bf(v.w));
        }
        #pragma unroll
        for (int pass = 0; pass < BN / 16; ++pass) {
            int r = pass * 16 + sr;
            const float4 v = *(const float4*)(&W[(size_t)(colBase + r) * INF + kk + sc * 4]);
            int off = r * 128 + ((sc * 8) ^ ((r & 7) << 4));
            *(ushort4*)((char*)Bs + off) =
                make_ushort4(f2bf(v.x), f2bf(v.y), f2bf(v.z), f2bf(v.w));
        }
        __syncthreads();
        #pragma unroll
        for (int ks = 0; ks < 2; ++ks) {
            short8v aF[2], bF[2];
            #pragma unroll
            for (int m = 0; m < 2; ++m) {
                int row = wm + m * 16 + (lane & 15);
                int cb  = (ks * 64 + ((lane >> 4) * 16)) ^ ((row & 7) << 4);
                aF[m] = *(const short8v*)((const char*)As + row * 128 + cb);
            }
            #pragma unroll
            for (int n = 0; n < 2; ++n) {
                int row = wn + n * 16 + (lane & 15);
                int cb  = (ks * 64 + ((lane >> 4) * 16)) ^ ((row & 7) << 4);
                bF[n] = *(const short8v*)((const char*)Bs + row * 128 + cb);
            }
            #pragma unroll
            for (int m = 0; m < 2; ++m)
                #pragma unroll
                for (int n = 0; n < 2; ++n)
                    acc[m][n] = __builtin_amdgcn_mfma_f32_16x16x32_bf16(
                        aF[m], bF[n], acc[m][n], 0, 0, 0);
        }
        __syncthreads();
    }
    // epilogue: C/D layout col=lane&15, row=(lane>>4)*4+reg
    const int r4 = (lane >> 4) * 4;
    const int cW = lane & 15;
    const int col0 = colBase + wn + cW;
    const int col1 = col0 + 16;
    const float b0 = bW[col0],  b1 = bW[col1];
    const float i0 = wai[col0], i1 = wai[col1];
    const float j0 = waj[col0], j1 = waj[col1];
    const int slot = (blockIdx.x >> 7) * 2 + (wid & 1);   // 8 x 32-col slices
    #pragma unroll
    for (int m = 0; m < 2; ++m) {
        #pragma unroll
        for (int r = 0; r < 4; ++r) {
            int row = rowBase + wm + m * 16 + r4 + r;
            float z0 = acc[m][0][r] + b0;
            float z1 = acc[m][1][r] + b1;
            zb[(size_t)row * OUTF + col0] = f2bf(z0);
            zb[(size_t)row * OUTF + col1] = f2bf(z1);
            float pi = z0 * i0 + z1 * i1;
            float pj = z0 * j0 + z1 * j1;
            #pragma unroll
            for (int s = 1; s < 16; s <<= 1) {   // 16-lane group reduce
                pi += __shfl_xor(pi, s);
                pj += __shfl_xor(pj, s);
            }
            if (cW == 0) {
                pai[row * 8 + slot] = pi;
                paj[row * 8 + slot] = pj;
            }
        }
    }
}

// ---------------------------------------------------- K2: sparse attention
// Wave per row (4/block, 2048 blocks, linear bid map). Lane holds mask word
// `lane`: j = (lane>>2)*256 + bit*4 + (lane&3). Popcount prefix-scan ->
// edge strip in per-wave LDS (no block barriers). Masked (-9e15) / sink
// (-1e9) reference terms underflow to exactly 0 for rows with edges;
// edgeless rows -> 0.
__global__ __launch_bounds__(256) void gat_attend(
        const unsigned long long* __restrict__ mask64,
        const float* __restrict__ pai, const float* __restrict__ paj,
        const float* __restrict__ bai, const float* __restrict__ baj,
        const unsigned short* __restrict__ zb, float* __restrict__ out) {
    __shared__ unsigned short s_idx[4][CAP_E];   // per-wave edge strip
    __shared__ float          s_w[4][CAP_E];
    const int tid  = threadIdx.x;
    const int lane = tid & 63;
    const int wv   = tid >> 6;
    const int row  = blockIdx.x * 4 + wv;
    const int b    = row >> 12;
    unsigned short* si = s_idx[wv];
    float* swv = s_w[wv];

    // compaction: 1 load + popcount prefix + per-lane bit extraction
    unsigned long long mm = mask64[(size_t)row * 64 + lane];
    const int c = __popcll(mm);
    int incl = c;
    #pragma unroll
    for (int s = 1; s < 64; s <<= 1) {
        int t = __shfl_up(incl, s);
        if (lane >= s) incl += t;
    }
    const int cnt0 = __shfl(incl, 63);
    const int cnt = cnt0 > CAP_E ? CAP_E : cnt0;
    int pos = incl - c;
    const int jbase = (lane >> 2) * 256 + (lane & 3);
    while (mm) {
        int bit = __builtin_ctzll(mm);
        if (pos < CAP_E) si[pos] = (unsigned short)(jbase + bit * 4);
        ++pos;
        mm &= mm - 1;
    }

    // AI = sum(pai[row]) + bai + baj  (both biases folded into the i-term)
    const float4* pa = (const float4*)(pai + row * 8);
    const float4 u = pa[0], v2 = pa[1];
    const float AI = (u.x + u.y + u.z + u.w) + (v2.x + v2.y + v2.z + v2.w)
                   + bai[0] + baj[0];

    // per-lane aj finalize for edge slots lane and lane+64 (cnt <= 128)
    const bool h0 = lane < cnt, h1 = lane + 64 < cnt;
    float a0 = -3e38f, a1 = -3e38f;
    const float* pjb = paj + ((size_t)(b << 12)) * 8;
    if (h0) {
        const float4* q = (const float4*)(pjb + si[lane] * 8);
        float4 x0 = q[0], x1 = q[1];
        a0 = (x0.x + x0.y + x0.z + x0.w) + (x1.x + x1.y + x1.z + x1.w);
    }
    if (h1) {
        const float4* q = (const float4*)(pjb + si[lane + 64] * 8);
        float4 x0 = q[0], x1 = q[1];
        a1 = (x0.x + x0.y + x0.z + x0.w) + (x1.x + x1.y + x1.z + x1.w);
    }
    float lm = fmaxf(a0, a1);
    #pragma unroll
    for (int s = 1; s < 64; s <<= 1) lm = fmaxf(lm, __shfl_xor(lm, s));
    const float tm = AI + lm;
    const float m = tm >= 0.f ? tm : 0.2f * tm;    // leaky is monotone
    float w0 = 0.f, w1 = 0.f;
    if (h0) { float e = AI + a0; e = e >= 0.f ? e : 0.2f * e; w0 = __expf(e - m); }
    if (h1) { float e = AI + a1; e = e >= 0.f ? e : 0.2f * e; w1 = __expf(e - m); }
    float ls = w0 + w1;
    #pragma unroll
    for (int s = 1; s < 64; s <<= 1) ls += __shfl_xor(ls, s);
    const float inv = cnt ? 1.f / ls : 0.f;
    if (h0) swv[lane] = w0;
    if (h1) swv[lane + 64] = w1;

    // gather: out[row][lane*4 .. +3] = inv * sum_p w_p * zb[j_p][cols]
    // unroll 8: 8 independent ushort4 loads in flight per iteration.
    const unsigned short* zcol = zb + ((size_t)(b << 12)) * OUTF + lane * 4;
    float4 acc = make_float4(0.f, 0.f, 0.f, 0.f);
    int p = 0;
    for (; p + 8 <= cnt; p += 8) {
        ushort4 q[8];
        float   w[8];
        #pragma unroll
        for (int k = 0; k < 8; ++k) {
            q[k] = *(const ushort4*)(zcol + (size_t)si[p + k] * OUTF);
            w[k] = swv[p + k];
        }
        #pragma unroll
        for (int k = 0; k < 8; ++k) {
            acc.x = fmaf(w[k], bf2f(q[k].x), acc.x);
            acc.y = fmaf(w[k], bf2f(q[k].y), acc.y);
            acc.z = fmaf(w[k], bf2f(q[k].z), acc.z);
            acc.w = fmaf(w[k], bf2f(q[k].w), acc.w);
        }
    }
    if (p + 4 <= cnt) {
        ushort4 q[4];
        float   w[4];
        #pragma unroll
        for (int k = 0; k < 4; ++k) {
            q[k] = *(const ushort4*)(zcol + (size_t)si[p + k] * OUTF);
            w[k] = swv[p + k];
        }
        #pragma unroll
        for (int k = 0; k < 4; ++k) {
            acc.x = fmaf(w[k], bf2f(q[k].x), acc.x);
            acc.y = fmaf(w[k], bf2f(q[k].y), acc.y);
            acc.z = fmaf(w[k], bf2f(q[k].z), acc.z);
            acc.w = fmaf(w[k], bf2f(q[k].w), acc.w);
        }
        p += 4;
    }
    for (; p < cnt; ++p) {
        int g = si[p]; float Wp = swv[p];
        ushort4 q = *(const ushort4*)(zcol + (size_t)g * OUTF);
        acc.x = fmaf(Wp, bf2f(q.x), acc.x);
        acc.y = fmaf(Wp, bf2f(q.y), acc.y);
        acc.z = fmaf(Wp, bf2f(q.z), acc.z);
        acc.w = fmaf(Wp, bf2f(q.w), acc.w);
    }
    *(float4*)(out + (size_t)row * OUTF + lane * 4) =
        make_float4(acc.x * inv, acc.y * inv, acc.z * inv, acc.w * inv);
}

extern "C" void kernel_launch(void* const* d_in, const int* in_sizes, int n_in,
                              void* d_out, int out_size, void* d_ws, size_t ws_size,
                              hipStream_t stream) {
    const float* x   = (const float*)d_in[0];
    const float* adj = (const float*)d_in[1];
    const float* W   = (const float*)d_in[2];
    const float* bW  = (const float*)d_in[3];
    const float* wai = (const float*)d_in[4];
    const float* bai = (const float*)d_in[5];
    const float* waj = (const float*)d_in[6];
    const float* baj = (const float*)d_in[7];
    float* out = (float*)d_out;

    char* ws = (char*)d_ws;
    unsigned short* zb   = (unsigned short*)ws;                    // 4 MB
    float* pai = (float*)(ws + (4u << 20));                        // 256 KB
    float* paj = pai + 8192 * 8;                                   // 256 KB
    unsigned long long* mask = (unsigned long long*)(ws + (5u << 20)); // 4 MB

    gat_pre<<<GEMM_BLOCKS + MASK_BLOCKS, 256, 0, stream>>>(
        x, W, bW, wai, waj, zb, pai, paj, adj, mask);
    gat_attend<<<2048, 256, 0, stream>>>(
        mask, pai, paj, bai, baj, zb, out);
}